// Round 11
// baseline (466.264 us; speedup 1.0000x reference)
//
#include <hip/hip_runtime.h>
#include <cstdint>

#define N_NODES 100000
#define N_EDGES 1600000
#define H 8
#define D 16
#define HD 128
#define G_GRAPHS 128
#define OUT_DIM 64
#define EPS 1e-3f
#define NEG 0.2f
#define NBUCK 196        // ceil(100000/512) dst buckets
#define BSHIFT 9         // 512 nodes per bucket
#define BCAP 10240       // per-bucket edge capacity (mean 8192, sigma~90)
#define MT 64            // GEMM rows per tile
#define APAD 136         // LDS A-tile row stride in halfs
#define NTILES 1563      // ceil(100000/64)
#define GEMM_GRID 512    // == 2 blocks/CU capacity
#define BNP_ROWS 64      // bn_pool rows per block
#define BNS_ROWS 128     // bn_stats rows per block (contiguous chunk)
#define WTROWS 144       // Wt rows: 128 W-cols + 8 el + 8 er
#define SRCMASK 0x1FFFF  // 17-bit src field in packed pair

typedef __attribute__((ext_vector_type(8))) short bf16x8;
typedef __attribute__((ext_vector_type(4))) float f32x4;
typedef __attribute__((ext_vector_type(8))) unsigned short u16x8;

__device__ __forceinline__ unsigned short f2bf(float x) {
    unsigned u = __float_as_uint(x);
    unsigned r = (u + 0x7FFFu + ((u >> 16) & 1u)) >> 16;  // RTNE
    return (unsigned short)r;
}
__device__ __forceinline__ float plo(unsigned q) {  // low bf16 of pair
    return __uint_as_float(q << 16);
}
__device__ __forceinline__ float phi(unsigned q) {  // high bf16 of pair
    return __uint_as_float(q & 0xFFFF0000u);
}
__device__ __forceinline__ unsigned packbf(float a, float b) {
    return (unsigned)f2bf(a) | ((unsigned)f2bf(b) << 16);
}

// ---- init (fused) + W -> bf16 transposed + appended wl/wr columns -------
__global__ void convert_wt(const float* __restrict__ W0, const float* __restrict__ W1,
                           const float* __restrict__ al0, const float* __restrict__ ar0,
                           const float* __restrict__ al1, const float* __restrict__ ar1,
                           unsigned short* __restrict__ Wt0, unsigned short* __restrict__ Wt1,
                           int* __restrict__ bucketCnt, float* __restrict__ pooled,
                           float* __restrict__ sums01) {
    int t = blockIdx.x * blockDim.x + threadIdx.x;
    if (t < NBUCK) bucketCnt[t] = 0;
    if (t < 512) sums01[t] = 0.f;
    for (int i = t; i < G_GRAPHS * HD; i += gridDim.x * blockDim.x) pooled[i] = 0.f;
    if (t < HD * HD) {
        int k = t >> 7, n = t & 127;
        Wt0[n * HD + k] = f2bf(W0[t]);
        Wt1[n * HD + k] = f2bf(W1[t]);
        return;
    }
    int u = t - HD * HD;
    if (u < HD * 16) {
        int k = u >> 4, j = u & 15;
        int h = j & 7;
        const float* a0 = (j < 8) ? al0 : ar0;
        const float* a1 = (j < 8) ? al1 : ar1;
        float s0 = 0.f, s1 = 0.f;
#pragma unroll
        for (int d = 0; d < 16; ++d) {
            s0 += W0[k * HD + h * 16 + d] * a0[h * 16 + d];
            s1 += W1[k * HD + h * 16 + d] * a1[h * 16 + d];
        }
        Wt0[(HD + j) * HD + k] = f2bf(s0);
        Wt1[(HD + j) * HD + k] = f2bf(s1);
    }
}

// ---- CSR build, phase A: bin edges into 196 coarse dst-buckets ----------
// Packed pair: (dstLocal:9b << 17) | (src:17b). int4-vectorized edge loads.
__global__ __launch_bounds__(256) void bucket_scatter(const int4* __restrict__ src4,
                                                      const int4* __restrict__ dst4,
                                                      int* __restrict__ bucketCnt,
                                                      int* __restrict__ pairs) {
    __shared__ int hist[NBUCK];
    __shared__ int cur[NBUCK];
    int t = threadIdx.x;
    if (t < NBUCK) hist[t] = 0;
    __syncthreads();
    int base4 = blockIdx.x * 1024;  // 4096 edges = 1024 int4
    const int NE4 = N_EDGES / 4;    // N_EDGES % 4 == 0
    int4 s[4], d[4];
    int valid[4];
#pragma unroll
    for (int k = 0; k < 4; ++k) {
        int i4 = base4 + t + k * 256;
        if (i4 < NE4) {
            s[k] = src4[i4];
            d[k] = dst4[i4];
            valid[k] = 1;
            atomicAdd(&hist[d[k].x >> BSHIFT], 1);
            atomicAdd(&hist[d[k].y >> BSHIFT], 1);
            atomicAdd(&hist[d[k].z >> BSHIFT], 1);
            atomicAdd(&hist[d[k].w >> BSHIFT], 1);
        } else {
            valid[k] = 0;
        }
    }
    __syncthreads();
    if (t < NBUCK) {
        int c = hist[t];
        cur[t] = (c > 0) ? atomicAdd(&bucketCnt[t], c) : 0;
    }
    __syncthreads();
#pragma unroll
    for (int k = 0; k < 4; ++k) {
        if (valid[k]) {
            int ss[4] = {s[k].x, s[k].y, s[k].z, s[k].w};
            int dd[4] = {d[k].x, d[k].y, d[k].z, d[k].w};
#pragma unroll
            for (int j = 0; j < 4; ++j) {
                int b = dd[j] >> BSHIFT;
                int slot = atomicAdd(&cur[b], 1);
                pairs[(size_t)b * BCAP + slot] = ((dd[j] & 511) << 17) | ss[j];
            }
        }
    }
}

// ---- CSR build, phase B (fused): hist + local scan + global base +
//      ninfo write + placement, per-bucket in one kernel ------------------
__global__ __launch_bounds__(256) void bucket_finish(const int* __restrict__ bucketCnt,
                                                     const int* __restrict__ pairs,
                                                     int2* __restrict__ ninfo,
                                                     int* __restrict__ csr_src) {
    __shared__ int hist[512];
    __shared__ int loc[512];
    __shared__ int bufA[256], bufB[256];
    __shared__ int bbase_sh;
    int b = blockIdx.x, t = threadIdx.x;
    int mycnt = bucketCnt[b];
    int base0 = b << BSHIFT;

    // ---- global bucket base: scan 196 bucket counts (redundant per block)
    bufA[t] = (t < NBUCK) ? bucketCnt[t] : 0;
    __syncthreads();
    {
        int* a = bufA; int* bb = bufB;
        for (int off = 1; off < 256; off <<= 1) {
            int val = a[t];
            if (t >= off) val += a[t - off];
            bb[t] = val;
            __syncthreads();
            int* c = a; a = bb; bb = c;
        }
        if (t == 0) bbase_sh = a[b] - mycnt;  // exclusive base of bucket b
    }
    // ---- per-node hist within bucket (int4-vectorized pairs reads)
    hist[t] = 0;
    hist[t + 256] = 0;
    __syncthreads();
    {
        const int4* p4 = (const int4*)&pairs[(size_t)b * BCAP];
        int n4 = mycnt >> 2;
        for (int i = t; i < n4; i += 256) {
            int4 w = p4[i];
            atomicAdd(&hist[(unsigned)w.x >> 17], 1);
            atomicAdd(&hist[(unsigned)w.y >> 17], 1);
            atomicAdd(&hist[(unsigned)w.z >> 17], 1);
            atomicAdd(&hist[(unsigned)w.w >> 17], 1);
        }
        for (int i = (n4 << 2) + t; i < mycnt; i += 256)
            atomicAdd(&hist[(unsigned)pairs[(size_t)b * BCAP + i] >> 17], 1);
    }
    __syncthreads();
    // ---- 512-entry local exclusive scan (2 elems/thread)
    int s0 = hist[2 * t], s1 = hist[2 * t + 1];
    int ps = s0 + s1;
    bufA[t] = ps;
    __syncthreads();
    int total_excl;
    {
        int* a = bufA; int* bb = bufB;
        for (int off = 1; off < 256; off <<= 1) {
            int val = a[t];
            if (t >= off) val += a[t - off];
            bb[t] = val;
            __syncthreads();
            int* c = a; a = bb; bb = c;
        }
        total_excl = a[t] - ps;  // exclusive pair offset
    }
    int bbase = bbase_sh;
    loc[2 * t] = total_excl;
    loc[2 * t + 1] = total_excl + s0;
    int n0 = base0 + 2 * t, n1 = base0 + 2 * t + 1;
    if (n0 < N_NODES) ninfo[n0] = make_int2(bbase + total_excl, s0);
    if (n1 < N_NODES) ninfo[n1] = make_int2(bbase + total_excl + s0, s1);
    __syncthreads();
    // ---- placement using LDS cursors (loc doubles as cur)
    {
        const int4* p4 = (const int4*)&pairs[(size_t)b * BCAP];
        int n4 = mycnt >> 2;
        for (int i = t; i < n4; i += 256) {
            int4 w = p4[i];
            int ws[4] = {w.x, w.y, w.z, w.w};
#pragma unroll
            for (int j = 0; j < 4; ++j) {
                int dl = (unsigned)ws[j] >> 17;
                int r = atomicAdd(&loc[dl], 1);
                csr_src[bbase + r] = ws[j] & SRCMASK;
            }
        }
        for (int i = (n4 << 2) + t; i < mycnt; i += 256) {
            int w = pairs[(size_t)b * BCAP + i];
            int dl = (unsigned)w >> 17;
            int r = atomicAdd(&loc[dl], 1);
            csr_src[bbase + r] = w & SRCMASK;
        }
    }
}

// ---- GEMM staging: load + convert one tile-row-slice into registers ----
template <int MODE>
__device__ __forceinline__ void stage_load(const void* __restrict__ Xv, int gr, int scol,
                                           int nrows, const float* scs, const float* shs,
                                           u16x8 o[4]) {
    if (gr < nrows) {
        if (MODE == 0) {
            const float* X = (const float*)Xv;
#pragma unroll
            for (int i = 0; i < 4; ++i) {
                float4 va = *(const float4*)&X[(size_t)gr * HD + scol + i * 8];
                float4 vb = *(const float4*)&X[(size_t)gr * HD + scol + i * 8 + 4];
                o[i][0] = f2bf(va.x); o[i][1] = f2bf(va.y);
                o[i][2] = f2bf(va.z); o[i][3] = f2bf(va.w);
                o[i][4] = f2bf(vb.x); o[i][5] = f2bf(vb.y);
                o[i][6] = f2bf(vb.z); o[i][7] = f2bf(vb.w);
            }
        } else {
            const unsigned* X32 = (const unsigned*)Xv;  // bf16 pairs
#pragma unroll
            for (int i = 0; i < 4; ++i) {
                uint4 u = *(const uint4*)&X32[(size_t)gr * 64 + (scol >> 1) + i * 4];
                f32x4 sa = *(const f32x4*)&scs[scol + i * 8];
                f32x4 sb = *(const f32x4*)&scs[scol + i * 8 + 4];
                f32x4 ha = *(const f32x4*)&shs[scol + i * 8];
                f32x4 hb = *(const f32x4*)&shs[scol + i * 8 + 4];
                float z0 = fmaxf(plo(u.x) * sa.x + ha.x, 0.f);
                float z1 = fmaxf(phi(u.x) * sa.y + ha.y, 0.f);
                float z2 = fmaxf(plo(u.y) * sa.z + ha.z, 0.f);
                float z3 = fmaxf(phi(u.y) * sa.w + ha.w, 0.f);
                float z4 = fmaxf(plo(u.z) * sb.x + hb.x, 0.f);
                float z5 = fmaxf(phi(u.z) * sb.y + hb.y, 0.f);
                float z6 = fmaxf(plo(u.w) * sb.z + hb.z, 0.f);
                float z7 = fmaxf(phi(u.w) * sb.w + hb.w, 0.f);
                o[i][0] = f2bf(z0); o[i][1] = f2bf(z1);
                o[i][2] = f2bf(z2); o[i][3] = f2bf(z3);
                o[i][4] = f2bf(z4); o[i][5] = f2bf(z5);
                o[i][6] = f2bf(z6); o[i][7] = f2bf(z7);
            }
        }
    } else {
#pragma unroll
        for (int i = 0; i < 4; ++i) o[i] = (u16x8)0;
    }
}

// ---- MFMA GEMM, 2-deep tile pipeline: stage(t+1) overlaps compute(t) ----
// Double-buffered LDS; next tile's global loads issue before the MFMA
// burst (no data dependence -> compiler hides load latency under MFMA).
// One barrier per tile. el/er fused as 9th output tile.
template <int MODE>
__global__ __launch_bounds__(256, 2) void gemm_mfma(const void* __restrict__ Xv,
                                                    const unsigned short* __restrict__ Wt,
                                                    unsigned short* __restrict__ Yb,
                                                    float* __restrict__ el,
                                                    float* __restrict__ er,
                                                    int nrows,
                                                    const float* __restrict__ sums,
                                                    const float* __restrict__ gam,
                                                    const float* __restrict__ bet) {
    __shared__ unsigned short As[2][MT * APAD];
    __shared__ __align__(16) float scs[HD];
    __shared__ __align__(16) float shs[HD];
    int tid = threadIdx.x;
    int wave = tid >> 6, lane = tid & 63;
    int qd = lane >> 4, l16 = lane & 15;

    if (MODE == 1) {
        if (tid < HD) {
            float invN = 1.0f / (float)N_NODES;
            float mu = sums[tid] * invN;
            float rs = rsqrtf(sums[HD + tid] * invN - mu * mu + EPS);
            float sc = rs * gam[tid];
            scs[tid] = sc;
            shs[tid] = bet[tid] - mu * sc;
        }
        __syncthreads();
    }

    bf16x8 bfr[9][4];
#pragma unroll
    for (int nt = 0; nt < 9; ++nt)
#pragma unroll
        for (int kb = 0; kb < 4; ++kb)
            bfr[nt][kb] = *(const bf16x8*)&Wt[(nt * 16 + l16) * HD + kb * 32 + qd * 8];

    int srow = tid >> 2, scol = (tid & 3) * 32;  // 4 threads/row, 32 halfs each

    u16x8 o[4];
    int t = blockIdx.x;
    // prologue: stage tile t into buffer 0
    stage_load<MODE>(Xv, t * MT + srow, scol, nrows, scs, shs, o);
#pragma unroll
    for (int i = 0; i < 4; ++i)
        *(u16x8*)&As[0][srow * APAD + scol + i * 8] = o[i];
    __syncthreads();
    int cur = 0;

    for (; t < NTILES; t += gridDim.x) {
        int tn = t + (int)gridDim.x;
        bool more = tn < NTILES;
        // issue next tile's loads (+convert) BEFORE the MFMA burst
        if (more)
            stage_load<MODE>(Xv, tn * MT + srow, scol, nrows, scs, shs, o);
        // compute current tile from As[cur]
        f32x4 acc[9];
#pragma unroll
        for (int nt = 0; nt < 9; ++nt) acc[nt] = (f32x4){0.f, 0.f, 0.f, 0.f};
        bf16x8 afr[4];
#pragma unroll
        for (int kb = 0; kb < 4; ++kb)
            afr[kb] = *(const bf16x8*)&As[cur][(wave * 16 + l16) * APAD + kb * 32 + qd * 8];
#pragma unroll
        for (int nt = 0; nt < 9; ++nt)
#pragma unroll
            for (int kb = 0; kb < 4; ++kb)
                acc[nt] = __builtin_amdgcn_mfma_f32_16x16x32_bf16(afr[kb], bfr[nt][kb], acc[nt], 0, 0, 0);
        int orow = t * MT + wave * 16 + qd * 4;
        if (orow + 3 < nrows) {
#pragma unroll
            for (int nt = 0; nt < 8; ++nt)
#pragma unroll
                for (int r = 0; r < 4; ++r)
                    Yb[(size_t)(orow + r) * HD + nt * 16 + l16] = f2bf(acc[nt][r]);
#pragma unroll
            for (int r = 0; r < 4; ++r) {
                float v = acc[8][r];
                if (l16 < 8) el[(orow + r) * 8 + l16] = v;
                else er[(orow + r) * 8 + (l16 - 8)] = v;
            }
        } else {
#pragma unroll
            for (int nt = 0; nt < 8; ++nt)
                for (int r = 0; r < 4; ++r)
                    if (orow + r < nrows)
                        Yb[(size_t)(orow + r) * HD + nt * 16 + l16] = f2bf(acc[nt][r]);
            for (int r = 0; r < 4; ++r) {
                if (orow + r < nrows) {
                    float v = acc[8][r];
                    if (l16 < 8) el[(orow + r) * 8 + l16] = v;
                    else er[(orow + r) * 8 + (l16 - 8)] = v;
                }
            }
        }
        // write staged tile into the other buffer
        if (more) {
#pragma unroll
            for (int i = 0; i < 4; ++i)
                *(u16x8*)&As[cur ^ 1][srow * APAD + scol + i * 8] = o[i];
        }
        __syncthreads();
        cur ^= 1;
    }
}

// ---- per-dst-node GAT, lane = (edge-slot x head) factorized (r1 best) ---
__global__ __launch_bounds__(256) void gat_node(const int2* __restrict__ ninfo,
                                                const int* __restrict__ csr_src,
                                                const float* __restrict__ el,
                                                const float* __restrict__ er,
                                                const uint2* __restrict__ featq,
                                                unsigned* __restrict__ gatb) {
    int node = blockIdx.x * 4 + (threadIdx.x >> 6);
    if (node >= N_NODES) return;
    int lane = threadIdx.x & 63;
    int h7 = lane & 7;        // phase-1 head
    int eidx = lane >> 3;     // phase-1 edge slot (0..7)
    int l32 = lane & 31;      // phase-2: owns cols 4*l32 .. 4*l32+3
    int hacc = l32 >> 2;      // phase-2 head
    int half = lane >> 5;     // 0: even slots, 1: odd slots
    int ibase = half * 8 + hacc;

    int2 pd = ninfo[node];
    int p = pd.x;
    int cnt = pd.y;
    float ern = er[node * 8 + h7];
    float ds = 0.f, a0 = 0.f, a1 = 0.f, a2 = 0.f, a3 = 0.f;

    int nfull = cnt & ~7;
    if (nfull) {
        int s = csr_src[p + eidx];
        float x = el[(unsigned)s * 8u + h7];
        int c = 0;
        for (;;) {
            float v = x + ern;
            v = fmaxf(v, NEG * v);
            float e = __expf(v);
            ds += e;
            int cn = c + 8;
            int snext = 0; float xnext = 0.f;
            if (cn < nfull) {
                snext = csr_src[p + cn + eidx];
                xnext = el[(unsigned)snext * 8u + h7];
            }
#pragma unroll
            for (int k = 0; k < 4; ++k) {
                float ek = __shfl(e, ibase + 16 * k);
                int sk = __shfl(s, ibase + 16 * k);
                uint2 q = featq[(size_t)((unsigned)sk * 32u + (unsigned)l32)];
                a0 += ek * plo(q.x); a1 += ek * phi(q.x);
                a2 += ek * plo(q.y); a3 += ek * phi(q.y);
            }
            if (cn >= nfull) break;
            c = cn; s = snext; x = xnext;
        }
    }
    int rem = cnt & 7;
    if (rem) {
        int s = 0; float e = 0.f;
        if (eidx < rem) {
            s = csr_src[p + nfull + eidx];
            float v = el[(unsigned)s * 8u + h7] + ern;
            v = fmaxf(v, NEG * v);
            e = __expf(v);
        }
        ds += e;
        int nst = (rem + 1) >> 1;  // odd tail's ghost edge has e=0, s=0
        for (int k = 0; k < nst; ++k) {
            float ek = __shfl(e, ibase + 16 * k);
            int sk = __shfl(s, ibase + 16 * k);
            uint2 q = featq[(size_t)((unsigned)sk * 32u + (unsigned)l32)];
            a0 += ek * plo(q.x); a1 += ek * phi(q.x);
            a2 += ek * plo(q.y); a3 += ek * phi(q.y);
        }
    }
    // full denominator per head (reduce over the 8 edge-slot lanes)
    ds += __shfl_xor(ds, 8);
    ds += __shfl_xor(ds, 16);
    ds += __shfl_xor(ds, 32);
    float dfull = __shfl(ds, hacc);
    float invd = dfull > 0.f ? 1.f / dfull : 0.f;
    // merge even/odd-slot halves
    a0 += __shfl_xor(a0, 32);
    a1 += __shfl_xor(a1, 32);
    a2 += __shfl_xor(a2, 32);
    a3 += __shfl_xor(a3, 32);
    if (half == 0) {
        uint2 w;
        w.x = packbf(a0 * invd, a1 * invd);
        w.y = packbf(a2 * invd, a3 * invd);
        ((uint2*)gatb)[(size_t)node * 32 + l32] = w;
    }
}

// ---- BN stats from bf16 input; contiguous 128-row chunks (782 blocks) ---
__global__ __launch_bounds__(256) void bn_stats(const unsigned* __restrict__ xb,
                                                float* __restrict__ sums, int nrows) {
    int cp = threadIdx.x & 63;   // col pair
    int rr = threadIdx.x >> 6;   // 0..3
    int r0 = blockIdx.x * BNS_ROWS;
    int rend = r0 + BNS_ROWS < nrows ? r0 + BNS_ROWS : nrows;
    float s0 = 0.f, q0 = 0.f, s1 = 0.f, q1 = 0.f;
    for (int r = r0 + rr; r < rend; r += 4) {
        unsigned u = xb[(size_t)r * 64 + cp];
        float a = plo(u), b = phi(u);
        s0 += a; q0 += a * a;
        s1 += b; q1 += b * b;
    }
    __shared__ float red[4][256];
    red[0][threadIdx.x] = s0;
    red[1][threadIdx.x] = q0;
    red[2][threadIdx.x] = s1;
    red[3][threadIdx.x] = q1;
    __syncthreads();
    if (rr == 0) {
        int c0 = cp * 2, c1 = c0 + 1;
        float ts0 = red[0][cp] + red[0][cp + 64] + red[0][cp + 128] + red[0][cp + 192];
        float tq0 = red[1][cp] + red[1][cp + 64] + red[1][cp + 128] + red[1][cp + 192];
        float ts1 = red[2][cp] + red[2][cp + 64] + red[2][cp + 128] + red[2][cp + 192];
        float tq1 = red[3][cp] + red[3][cp + 64] + red[3][cp + 128] + red[3][cp + 192];
        atomicAdd(&sums[c0], ts0);
        atomicAdd(&sums[128 + c0], tq0);
        atomicAdd(&sums[c1], ts1);
        atomicAdd(&sums[128 + c1], tq1);
    }
}

// ---- layer-1 epilogue fused: bn1 + relu + recomputed-h1 residual + pool --
__global__ __launch_bounds__(256) void bn_pool(const unsigned* __restrict__ gat1,
                                               const float* __restrict__ sums1,
                                               const float* __restrict__ g1v,
                                               const float* __restrict__ be1v,
                                               const unsigned* __restrict__ gat0,
                                               const float* __restrict__ sums0,
                                               const float* __restrict__ g0v,
                                               const float* __restrict__ be0v,
                                               const int* __restrict__ gid,
                                               float* __restrict__ pooled) {
    int cp = threadIdx.x & 63;
    int rr = threadIdx.x >> 6;
    int c0 = cp * 2, c1 = c0 + 1;
    float invN = 1.0f / (float)N_NODES;
    float mu10 = sums1[c0] * invN, mu11 = sums1[c1] * invN;
    float rs10 = rsqrtf(sums1[128 + c0] * invN - mu10 * mu10 + EPS);
    float rs11 = rsqrtf(sums1[128 + c1] * invN - mu11 * mu11 + EPS);
    float A10 = rs10 * g1v[c0], B10 = be1v[c0] - mu10 * A10;
    float A11 = rs11 * g1v[c1], B11 = be1v[c1] - mu11 * A11;
    float mu00 = sums0[c0] * invN, mu01 = sums0[c1] * invN;
    float rs00 = rsqrtf(sums0[128 + c0] * invN - mu00 * mu00 + EPS);
    float rs01 = rsqrtf(sums0[128 + c1] * invN - mu01 * mu01 + EPS);
    float A00 = rs00 * g0v[c0], B00 = be0v[c0] - mu00 * A00;
    float A01 = rs01 * g0v[c1], B01 = be0v[c1] - mu01 * A01;
    int r0 = blockIdx.x * BNP_ROWS;
    int rend = r0 + BNP_ROWS < N_NODES ? r0 + BNP_ROWS : N_NODES;
    int r = r0 + rr;
    if (r >= rend) return;
    float a0 = 0.f, a1 = 0.f;
    int cur = gid[r];
    for (; r < rend; r += 4) {
        int gg = gid[r];
        if (gg != cur) {
            atomicAdd(&pooled[cur * HD + c0], a0);
            atomicAdd(&pooled[cur * HD + c1], a1);
            a0 = a1 = 0.f;
            cur = gg;
        }
        unsigned u = gat1[(size_t)r * 64 + cp];
        float z0 = plo(u) * A10 + B10;
        float z1 = phi(u) * A11 + B11;
        z0 = z0 > 0.f ? z0 : 0.f;
        z1 = z1 > 0.f ? z1 : 0.f;
        unsigned v = gat0[(size_t)r * 64 + cp];
        float h0 = plo(v) * A00 + B00;
        float h1 = phi(v) * A01 + B01;
        h0 = h0 > 0.f ? h0 : 0.f;
        h1 = h1 > 0.f ? h1 : 0.f;
        a0 += z0 + h0;
        a1 += z1 + h1;
    }
    atomicAdd(&pooled[cur * HD + c0], a0);
    atomicAdd(&pooled[cur * HD + c1], a1);
}

// ---- masked prediction head ---------------------------------------------
__global__ void pred_kernel(const float* __restrict__ pooled, const float* __restrict__ W,
                            const float* __restrict__ b, const float* __restrict__ mask,
                            float* __restrict__ out) {
    int t = blockIdx.x * blockDim.x + threadIdx.x;
    if (t >= G_GRAPHS * OUT_DIM) return;
    int g = t >> 6, o = t & 63;
    float acc = b[o];
#pragma unroll 4
    for (int c = 0; c < HD; ++c) {
        float m = mask[o * HD + c] > 0.5f ? 1.f : 0.f;
        acc += pooled[g * HD + c] * W[o * HD + c] * m;
    }
    out[t] = acc;
}

extern "C" void kernel_launch(void* const* d_in, const int* in_sizes, int n_in,
                              void* d_out, int out_size, void* d_ws, size_t ws_size,
                              hipStream_t stream) {
    const float* h   = (const float*)d_in[0];
    const int*   src = (const int*)d_in[1];
    const int*   dst = (const int*)d_in[2];
    const int*   gid = (const int*)d_in[3];
    const float* W0  = (const float*)d_in[4];
    const float* al0 = (const float*)d_in[5];
    const float* ar0 = (const float*)d_in[6];
    // d_in[7] = b0 — BN shift-invariance: bias cancels exactly
    const float* g0  = (const float*)d_in[8];
    const float* be0 = (const float*)d_in[9];
    const float* W1  = (const float*)d_in[10];
    const float* al1 = (const float*)d_in[11];
    const float* ar1 = (const float*)d_in[12];
    // d_in[13] = b1 — cancels
    const float* g1  = (const float*)d_in[14];
    const float* be1 = (const float*)d_in[15];
    const float* pW  = (const float*)d_in[16];
    const float* pb  = (const float*)d_in[17];
    const float* msk = (const float*)d_in[18];
    float* out = (float*)d_out;

    // workspace layout
    unsigned short* gat0  = (unsigned short*)d_ws;                 // [N,128] bf16 layer-0 gat out
    unsigned short* gat1  = gat0 + (size_t)N_NODES * HD;           // [N,128] bf16 layer-1 gat out
    unsigned short* featb = gat1 + (size_t)N_NODES * HD;           // [N,128] bf16
    float* el   = (float*)(featb + (size_t)N_NODES * HD);          // [N,8]
    float* er   = el + (size_t)N_NODES * H;                        // [N,8]
    int2*  ninfo = (int2*)(er + (size_t)N_NODES * H);              // [N] (offs,deg)
    int*   csr_src = (int*)(ninfo + N_NODES);                      // [E]
    int*   bucketCnt = csr_src + N_EDGES;                          // [256]
    float* sums0  = (float*)(bucketCnt + 256);                     // [256]
    float* sums1  = sums0 + 256;                                   // [256]
    float* pooled = sums1 + 256;                                   // [128,128]
    unsigned short* wt0 = (unsigned short*)(pooled + G_GRAPHS * HD); // [144,128] bf16
    unsigned short* wt1 = wt0 + WTROWS * HD;                         // [144,128] bf16
    // pairs aliased over gat1 (8.0 MB < 25.6 MB; dead before layer-1 gat_node writes gat1)
    int*   pairs  = (int*)gat1;

    const int TB = 256;
    dim3 blk(TB);
    int bsc_blocks  = (N_EDGES + 4095) / 4096;
    int node_blocks = (N_NODES + 3) / 4;
    int bns_blocks  = (N_NODES + BNS_ROWS - 1) / BNS_ROWS;
    int bnp_blocks  = (N_NODES + BNP_ROWS - 1) / BNP_ROWS;
    int cw_blocks   = (HD * HD + HD * 16 + TB - 1) / TB;

    // ---------------- CSR build + weight convert (init fused) ------------
    convert_wt<<<cw_blocks, blk, 0, stream>>>(W0, W1, al0, ar0, al1, ar1, wt0, wt1,
                                              bucketCnt, pooled, sums0);
    bucket_scatter<<<bsc_blocks, blk, 0, stream>>>((const int4*)src, (const int4*)dst,
                                                   bucketCnt, pairs);
    bucket_finish<<<NBUCK, blk, 0, stream>>>(bucketCnt, pairs, ninfo, csr_src);

    // ---------------- layer 0 (el/er fused into GEMM) ----------------
    gemm_mfma<0><<<GEMM_GRID, blk, 0, stream>>>(h, wt0, featb, el, er, N_NODES,
                                                nullptr, nullptr, nullptr);
    gat_node<<<node_blocks, blk, 0, stream>>>(ninfo, csr_src, el, er,
                                              (const uint2*)featb, (unsigned*)gat0);
    bn_stats<<<bns_blocks, blk, 0, stream>>>((const unsigned*)gat0, sums0, N_NODES);

    // ---------------- layer 1 (BN0+ReLU fused into GEMM A-staging) --------
    gemm_mfma<1><<<GEMM_GRID, blk, 0, stream>>>(gat0, wt1, featb, el, er, N_NODES,
                                                sums0, g0, be0);
    gat_node<<<node_blocks, blk, 0, stream>>>(ninfo, csr_src, el, er,
                                              (const uint2*)featb, (unsigned*)gat1);
    bn_stats<<<bns_blocks, blk, 0, stream>>>((const unsigned*)gat1, sums1, N_NODES);
    // fused: bn1 + relu + residual(recomputed h1 from gat0) + graph sum-pool
    bn_pool<<<bnp_blocks, blk, 0, stream>>>((const unsigned*)gat1, sums1, g1, be1,
                                            (const unsigned*)gat0, sums0, g0, be0,
                                            gid, pooled);

    // ---------------- head ----------------
    pred_kernel<<<(G_GRAPHS * OUT_DIM + TB - 1) / TB, blk, 0, stream>>>(pooled, pW, pb, msk, out);
}

// Round 12
// 430.253 us; speedup vs baseline: 1.0837x; 1.0837x over previous
//
#include <hip/hip_runtime.h>
#include <cstdint>

#define N_NODES 100000
#define N_EDGES 1600000
#define H 8
#define D 16
#define HD 128
#define G_GRAPHS 128
#define OUT_DIM 64
#define EPS 1e-3f
#define NEG 0.2f
#define NBUCK 196        // ceil(100000/512) dst buckets
#define BSHIFT 9         // 512 nodes per bucket
#define BCAP 10240       // per-bucket edge capacity (mean 8192, sigma~90)
#define MT 64            // GEMM rows per tile
#define APAD 136         // LDS A-tile row stride in halfs
#define NTILES 1563      // ceil(100000/64)
#define GEMM_GRID 512    // == 2 blocks/CU capacity
#define BNP_ROWS 64      // bn_pool rows per block
#define BNS_ROWS 128     // bn_stats rows per block (contiguous chunk)
#define WTROWS 144       // Wt rows: 128 W-cols + 8 el + 8 er
#define SRCMASK 0x1FFFF  // 17-bit src field in packed pair

typedef __attribute__((ext_vector_type(8))) short bf16x8;
typedef __attribute__((ext_vector_type(4))) float f32x4;
typedef __attribute__((ext_vector_type(8))) unsigned short u16x8;

__device__ __forceinline__ unsigned short f2bf(float x) {
    unsigned u = __float_as_uint(x);
    unsigned r = (u + 0x7FFFu + ((u >> 16) & 1u)) >> 16;  // RTNE
    return (unsigned short)r;
}
__device__ __forceinline__ float plo(unsigned q) {  // low bf16 of pair
    return __uint_as_float(q << 16);
}
__device__ __forceinline__ float phi(unsigned q) {  // high bf16 of pair
    return __uint_as_float(q & 0xFFFF0000u);
}
__device__ __forceinline__ unsigned packbf(float a, float b) {
    return (unsigned)f2bf(a) | ((unsigned)f2bf(b) << 16);
}

// decode 8 fp8 (uint2) and accumulate with weight ee into a[0..7]
#define ACC8(qq, ee) do { \
    auto f0_ = __builtin_amdgcn_cvt_pk_f32_fp8((qq).x, false); \
    a[0] += (ee) * f0_[0]; a[1] += (ee) * f0_[1]; \
    auto f1_ = __builtin_amdgcn_cvt_pk_f32_fp8((qq).x, true); \
    a[2] += (ee) * f1_[0]; a[3] += (ee) * f1_[1]; \
    auto f2_ = __builtin_amdgcn_cvt_pk_f32_fp8((qq).y, false); \
    a[4] += (ee) * f2_[0]; a[5] += (ee) * f2_[1]; \
    auto f3_ = __builtin_amdgcn_cvt_pk_f32_fp8((qq).y, true); \
    a[6] += (ee) * f3_[0]; a[7] += (ee) * f3_[1]; \
} while (0)

// ---- init (fused) + W -> bf16 transposed/PERMUTED + appended wl/wr ------
// Wt row n (n<128) holds W column f = 8*(n&15) + (n>>4): the MFMA output
// lane l16 then owns CONTIGUOUS features 8*l16..8*l16+7 across the 8 tiles,
// so the fp8 pack is lane-local. Rows 128..143: el/er fold (natural order).
__global__ void convert_wt(const float* __restrict__ W0, const float* __restrict__ W1,
                           const float* __restrict__ al0, const float* __restrict__ ar0,
                           const float* __restrict__ al1, const float* __restrict__ ar1,
                           unsigned short* __restrict__ Wt0, unsigned short* __restrict__ Wt1,
                           int* __restrict__ bucketCnt, float* __restrict__ pooled,
                           float* __restrict__ sums01) {
    int t = blockIdx.x * blockDim.x + threadIdx.x;
    if (t < NBUCK) bucketCnt[t] = 0;
    if (t < 512) sums01[t] = 0.f;
    for (int i = t; i < G_GRAPHS * HD; i += gridDim.x * blockDim.x) pooled[i] = 0.f;
    if (t < HD * HD) {
        int k = t >> 7, n = t & 127;
        int f = ((n & 15) << 3) | (n >> 4);  // fp8-pack locality permutation
        Wt0[n * HD + k] = f2bf(W0[k * HD + f]);
        Wt1[n * HD + k] = f2bf(W1[k * HD + f]);
        return;
    }
    int u = t - HD * HD;
    if (u < HD * 16) {
        int k = u >> 4, j = u & 15;
        int h = j & 7;
        const float* a0 = (j < 8) ? al0 : ar0;
        const float* a1 = (j < 8) ? al1 : ar1;
        float s0 = 0.f, s1 = 0.f;
#pragma unroll
        for (int d = 0; d < 16; ++d) {
            s0 += W0[k * HD + h * 16 + d] * a0[h * 16 + d];
            s1 += W1[k * HD + h * 16 + d] * a1[h * 16 + d];
        }
        Wt0[(HD + j) * HD + k] = f2bf(s0);
        Wt1[(HD + j) * HD + k] = f2bf(s1);
    }
}

// ---- CSR build, phase A: bin edges into 196 coarse dst-buckets ----------
// Packed pair: (dstLocal:9b << 17) | (src:17b). int4-vectorized edge loads.
__global__ __launch_bounds__(256) void bucket_scatter(const int4* __restrict__ src4,
                                                      const int4* __restrict__ dst4,
                                                      int* __restrict__ bucketCnt,
                                                      int* __restrict__ pairs) {
    __shared__ int hist[NBUCK];
    __shared__ int cur[NBUCK];
    int t = threadIdx.x;
    if (t < NBUCK) hist[t] = 0;
    __syncthreads();
    int base4 = blockIdx.x * 1024;  // 4096 edges = 1024 int4
    const int NE4 = N_EDGES / 4;    // N_EDGES % 4 == 0
    int4 s[4], d[4];
    int valid[4];
#pragma unroll
    for (int k = 0; k < 4; ++k) {
        int i4 = base4 + t + k * 256;
        if (i4 < NE4) {
            s[k] = src4[i4];
            d[k] = dst4[i4];
            valid[k] = 1;
            atomicAdd(&hist[d[k].x >> BSHIFT], 1);
            atomicAdd(&hist[d[k].y >> BSHIFT], 1);
            atomicAdd(&hist[d[k].z >> BSHIFT], 1);
            atomicAdd(&hist[d[k].w >> BSHIFT], 1);
        } else {
            valid[k] = 0;
        }
    }
    __syncthreads();
    if (t < NBUCK) {
        int c = hist[t];
        cur[t] = (c > 0) ? atomicAdd(&bucketCnt[t], c) : 0;
    }
    __syncthreads();
#pragma unroll
    for (int k = 0; k < 4; ++k) {
        if (valid[k]) {
            int ss[4] = {s[k].x, s[k].y, s[k].z, s[k].w};
            int dd[4] = {d[k].x, d[k].y, d[k].z, d[k].w};
#pragma unroll
            for (int j = 0; j < 4; ++j) {
                int b = dd[j] >> BSHIFT;
                int slot = atomicAdd(&cur[b], 1);
                pairs[(size_t)b * BCAP + slot] = ((dd[j] & 511) << 17) | ss[j];
            }
        }
    }
}

// ---- CSR build, phase B (fused): hist + local scan + global base +
//      ninfo write + placement, per-bucket in one kernel ------------------
__global__ __launch_bounds__(256) void bucket_finish(const int* __restrict__ bucketCnt,
                                                     const int* __restrict__ pairs,
                                                     int2* __restrict__ ninfo,
                                                     int* __restrict__ csr_src) {
    __shared__ int hist[512];
    __shared__ int loc[512];
    __shared__ int bufA[256], bufB[256];
    __shared__ int bbase_sh;
    int b = blockIdx.x, t = threadIdx.x;
    int mycnt = bucketCnt[b];
    int base0 = b << BSHIFT;

    // ---- global bucket base: scan 196 bucket counts (redundant per block)
    bufA[t] = (t < NBUCK) ? bucketCnt[t] : 0;
    __syncthreads();
    {
        int* a = bufA; int* bb = bufB;
        for (int off = 1; off < 256; off <<= 1) {
            int val = a[t];
            if (t >= off) val += a[t - off];
            bb[t] = val;
            __syncthreads();
            int* c = a; a = bb; bb = c;
        }
        if (t == 0) bbase_sh = a[b] - mycnt;  // exclusive base of bucket b
    }
    // ---- per-node hist within bucket (int4-vectorized pairs reads)
    hist[t] = 0;
    hist[t + 256] = 0;
    __syncthreads();
    {
        const int4* p4 = (const int4*)&pairs[(size_t)b * BCAP];
        int n4 = mycnt >> 2;
        for (int i = t; i < n4; i += 256) {
            int4 w = p4[i];
            atomicAdd(&hist[(unsigned)w.x >> 17], 1);
            atomicAdd(&hist[(unsigned)w.y >> 17], 1);
            atomicAdd(&hist[(unsigned)w.z >> 17], 1);
            atomicAdd(&hist[(unsigned)w.w >> 17], 1);
        }
        for (int i = (n4 << 2) + t; i < mycnt; i += 256)
            atomicAdd(&hist[(unsigned)pairs[(size_t)b * BCAP + i] >> 17], 1);
    }
    __syncthreads();
    // ---- 512-entry local exclusive scan (2 elems/thread)
    int s0 = hist[2 * t], s1 = hist[2 * t + 1];
    int ps = s0 + s1;
    bufA[t] = ps;
    __syncthreads();
    int total_excl;
    {
        int* a = bufA; int* bb = bufB;
        for (int off = 1; off < 256; off <<= 1) {
            int val = a[t];
            if (t >= off) val += a[t - off];
            bb[t] = val;
            __syncthreads();
            int* c = a; a = bb; bb = c;
        }
        total_excl = a[t] - ps;  // exclusive pair offset
    }
    int bbase = bbase_sh;
    loc[2 * t] = total_excl;
    loc[2 * t + 1] = total_excl + s0;
    int n0 = base0 + 2 * t, n1 = base0 + 2 * t + 1;
    if (n0 < N_NODES) ninfo[n0] = make_int2(bbase + total_excl, s0);
    if (n1 < N_NODES) ninfo[n1] = make_int2(bbase + total_excl + s0, s1);
    __syncthreads();
    // ---- placement using LDS cursors (loc doubles as cur)
    {
        const int4* p4 = (const int4*)&pairs[(size_t)b * BCAP];
        int n4 = mycnt >> 2;
        for (int i = t; i < n4; i += 256) {
            int4 w = p4[i];
            int ws[4] = {w.x, w.y, w.z, w.w};
#pragma unroll
            for (int j = 0; j < 4; ++j) {
                int dl = (unsigned)ws[j] >> 17;
                int r = atomicAdd(&loc[dl], 1);
                csr_src[bbase + r] = ws[j] & SRCMASK;
            }
        }
        for (int i = (n4 << 2) + t; i < mycnt; i += 256) {
            int w = pairs[(size_t)b * BCAP + i];
            int dl = (unsigned)w >> 17;
            int r = atomicAdd(&loc[dl], 1);
            csr_src[bbase + r] = w & SRCMASK;
        }
    }
}

// ---- GEMM staging: load + convert one tile-row-slice into registers ----
template <int MODE>
__device__ __forceinline__ void stage_load(const void* __restrict__ Xv, int gr, int scol,
                                           int nrows, const float* scs, const float* shs,
                                           u16x8 o[4]) {
    if (gr < nrows) {
        if (MODE == 0) {
            const float* X = (const float*)Xv;
#pragma unroll
            for (int i = 0; i < 4; ++i) {
                float4 va = *(const float4*)&X[(size_t)gr * HD + scol + i * 8];
                float4 vb = *(const float4*)&X[(size_t)gr * HD + scol + i * 8 + 4];
                o[i][0] = f2bf(va.x); o[i][1] = f2bf(va.y);
                o[i][2] = f2bf(va.z); o[i][3] = f2bf(va.w);
                o[i][4] = f2bf(vb.x); o[i][5] = f2bf(vb.y);
                o[i][6] = f2bf(vb.z); o[i][7] = f2bf(vb.w);
            }
        } else {
            const unsigned* X32 = (const unsigned*)Xv;  // bf16 pairs
#pragma unroll
            for (int i = 0; i < 4; ++i) {
                uint4 u = *(const uint4*)&X32[(size_t)gr * 64 + (scol >> 1) + i * 4];
                f32x4 sa = *(const f32x4*)&scs[scol + i * 8];
                f32x4 sb = *(const f32x4*)&scs[scol + i * 8 + 4];
                f32x4 ha = *(const f32x4*)&shs[scol + i * 8];
                f32x4 hb = *(const f32x4*)&shs[scol + i * 8 + 4];
                float z0 = fmaxf(plo(u.x) * sa.x + ha.x, 0.f);
                float z1 = fmaxf(phi(u.x) * sa.y + ha.y, 0.f);
                float z2 = fmaxf(plo(u.y) * sa.z + ha.z, 0.f);
                float z3 = fmaxf(phi(u.y) * sa.w + ha.w, 0.f);
                float z4 = fmaxf(plo(u.z) * sb.x + hb.x, 0.f);
                float z5 = fmaxf(phi(u.z) * sb.y + hb.y, 0.f);
                float z6 = fmaxf(plo(u.w) * sb.z + hb.z, 0.f);
                float z7 = fmaxf(phi(u.w) * sb.w + hb.w, 0.f);
                o[i][0] = f2bf(z0); o[i][1] = f2bf(z1);
                o[i][2] = f2bf(z2); o[i][3] = f2bf(z3);
                o[i][4] = f2bf(z4); o[i][5] = f2bf(z5);
                o[i][6] = f2bf(z6); o[i][7] = f2bf(z7);
            }
        }
    } else {
#pragma unroll
        for (int i = 0; i < 4; ++i) o[i] = (u16x8)0;
    }
}

// ---- MFMA GEMM, 2-deep tile pipeline; feat output packed fp8 e4m3.
// With the Wt permutation, lane l16 holds features 8*l16..8*l16+7 across
// the 8 tiles -> lane-local uint2 pack via v_cvt_pk_fp8_f32.
// el/er fused as 9th output tile (fp32 from accumulators, unchanged).
template <int MODE>
__global__ __launch_bounds__(256, 2) void gemm_mfma(const void* __restrict__ Xv,
                                                    const unsigned short* __restrict__ Wt,
                                                    uint2* __restrict__ Y8,
                                                    float* __restrict__ el,
                                                    float* __restrict__ er,
                                                    int nrows,
                                                    const float* __restrict__ sums,
                                                    const float* __restrict__ gam,
                                                    const float* __restrict__ bet) {
    __shared__ unsigned short As[2][MT * APAD];
    __shared__ __align__(16) float scs[HD];
    __shared__ __align__(16) float shs[HD];
    int tid = threadIdx.x;
    int wave = tid >> 6, lane = tid & 63;
    int qd = lane >> 4, l16 = lane & 15;

    if (MODE == 1) {
        if (tid < HD) {
            float invN = 1.0f / (float)N_NODES;
            float mu = sums[tid] * invN;
            float rs = rsqrtf(sums[HD + tid] * invN - mu * mu + EPS);
            float sc = rs * gam[tid];
            scs[tid] = sc;
            shs[tid] = bet[tid] - mu * sc;
        }
        __syncthreads();
    }

    bf16x8 bfr[9][4];
#pragma unroll
    for (int nt = 0; nt < 9; ++nt)
#pragma unroll
        for (int kb = 0; kb < 4; ++kb)
            bfr[nt][kb] = *(const bf16x8*)&Wt[(nt * 16 + l16) * HD + kb * 32 + qd * 8];

    int srow = tid >> 2, scol = (tid & 3) * 32;  // 4 threads/row, 32 halfs each

    u16x8 o[4];
    int t = blockIdx.x;
    // prologue: stage tile t into buffer 0
    stage_load<MODE>(Xv, t * MT + srow, scol, nrows, scs, shs, o);
#pragma unroll
    for (int i = 0; i < 4; ++i)
        *(u16x8*)&As[0][srow * APAD + scol + i * 8] = o[i];
    __syncthreads();
    int cur = 0;

    for (; t < NTILES; t += gridDim.x) {
        int tn = t + (int)gridDim.x;
        bool more = tn < NTILES;
        // issue next tile's loads (+convert) BEFORE the MFMA burst
        if (more)
            stage_load<MODE>(Xv, tn * MT + srow, scol, nrows, scs, shs, o);
        // compute current tile from As[cur]
        f32x4 acc[9];
#pragma unroll
        for (int nt = 0; nt < 9; ++nt) acc[nt] = (f32x4){0.f, 0.f, 0.f, 0.f};
        bf16x8 afr[4];
#pragma unroll
        for (int kb = 0; kb < 4; ++kb)
            afr[kb] = *(const bf16x8*)&As[cur][(wave * 16 + l16) * APAD + kb * 32 + qd * 8];
#pragma unroll
        for (int nt = 0; nt < 9; ++nt)
#pragma unroll
            for (int kb = 0; kb < 4; ++kb)
                acc[nt] = __builtin_amdgcn_mfma_f32_16x16x32_bf16(afr[kb], bfr[nt][kb], acc[nt], 0, 0, 0);
        int orow = t * MT + wave * 16 + qd * 4;
        if (orow + 3 < nrows) {
#pragma unroll
            for (int r = 0; r < 4; ++r) {
                unsigned lo = 0, hi = 0;
                lo = __builtin_amdgcn_cvt_pk_fp8_f32(acc[0][r], acc[1][r], lo, false);
                lo = __builtin_amdgcn_cvt_pk_fp8_f32(acc[2][r], acc[3][r], lo, true);
                hi = __builtin_amdgcn_cvt_pk_fp8_f32(acc[4][r], acc[5][r], hi, false);
                hi = __builtin_amdgcn_cvt_pk_fp8_f32(acc[6][r], acc[7][r], hi, true);
                Y8[(size_t)(orow + r) * 16 + l16] = make_uint2(lo, hi);
            }
#pragma unroll
            for (int r = 0; r < 4; ++r) {
                float v = acc[8][r];
                if (l16 < 8) el[(orow + r) * 8 + l16] = v;
                else er[(orow + r) * 8 + (l16 - 8)] = v;
            }
        } else {
            for (int r = 0; r < 4; ++r) {
                if (orow + r < nrows) {
                    unsigned lo = 0, hi = 0;
                    lo = __builtin_amdgcn_cvt_pk_fp8_f32(acc[0][r], acc[1][r], lo, false);
                    lo = __builtin_amdgcn_cvt_pk_fp8_f32(acc[2][r], acc[3][r], lo, true);
                    hi = __builtin_amdgcn_cvt_pk_fp8_f32(acc[4][r], acc[5][r], hi, false);
                    hi = __builtin_amdgcn_cvt_pk_fp8_f32(acc[6][r], acc[7][r], hi, true);
                    Y8[(size_t)(orow + r) * 16 + l16] = make_uint2(lo, hi);
                    float v = acc[8][r];
                    if (l16 < 8) el[(orow + r) * 8 + l16] = v;
                    else er[(orow + r) * 8 + (l16 - 8)] = v;
                }
            }
        }
        // write staged tile into the other buffer
        if (more) {
#pragma unroll
            for (int i = 0; i < 4; ++i)
                *(u16x8*)&As[cur ^ 1][srow * APAD + scol + i * 8] = o[i];
        }
        __syncthreads();
        cur ^= 1;
    }
}

// ---- per-dst-node GAT, fp8 feat rows (128 B): 16 lanes/row, one VMEM
// instruction serves 4 edges. Lane l16 owns contiguous features
// 8*l16..8*l16+7 (all in head (l16>>1)); subgroup sub=lane>>4 gathers
// slots {sub, sub+4} of each 8-edge chunk. Phase 1 + pipeline unchanged.
__global__ __launch_bounds__(256) void gat_node(const int2* __restrict__ ninfo,
                                                const int* __restrict__ csr_src,
                                                const float* __restrict__ el,
                                                const float* __restrict__ er,
                                                const uint2* __restrict__ feat8q,
                                                unsigned* __restrict__ gatb) {
    int node = blockIdx.x * 4 + (threadIdx.x >> 6);
    if (node >= N_NODES) return;
    int lane = threadIdx.x & 63;
    int h7 = lane & 7;        // phase-1 head
    int eidx = lane >> 3;     // phase-1 edge slot (0..7)
    int l16 = lane & 15;      // phase-2 row-lane
    int sub = lane >> 4;      // phase-2 subgroup (slots sub, sub+4)
    int hacc8 = l16 >> 1;     // head of owned features
    int sl0 = sub * 8 + hacc8;    // shfl src for slot sub
    int sl1 = sl0 + 32;           // shfl src for slot sub+4

    int2 pd = ninfo[node];
    int p = pd.x;
    int cnt = pd.y;
    float ern = er[node * 8 + h7];
    float ds = 0.f;
    float a[8];
#pragma unroll
    for (int i = 0; i < 8; ++i) a[i] = 0.f;

    int nfull = cnt & ~7;
    if (nfull) {
        int s = csr_src[p + eidx];
        float x = el[(unsigned)s * 8u + h7];
        int c = 0;
        for (;;) {
            float v = x + ern;
            v = fmaxf(v, NEG * v);
            float e = __expf(v);
            ds += e;
            int cn = c + 8;
            int snext = 0; float xnext = 0.f;
            if (cn < nfull) {
                snext = csr_src[p + cn + eidx];
                xnext = el[(unsigned)snext * 8u + h7];
            }
            float e0 = __shfl(e, sl0); int s0 = __shfl(s, sl0);
            float e1 = __shfl(e, sl1); int s1 = __shfl(s, sl1);
            uint2 q0 = feat8q[(size_t)((unsigned)s0 * 16u + (unsigned)l16)];
            uint2 q1 = feat8q[(size_t)((unsigned)s1 * 16u + (unsigned)l16)];
            ACC8(q0, e0);
            ACC8(q1, e1);
            if (cn >= nfull) break;
            c = cn; s = snext; x = xnext;
        }
    }
    int rem = cnt & 7;
    if (rem) {
        int s = 0; float e = 0.f;
        if (eidx < rem) {
            s = csr_src[p + nfull + eidx];
            float v = el[(unsigned)s * 8u + h7] + ern;
            v = fmaxf(v, NEG * v);
            e = __expf(v);
        }
        ds += e;
        float e0 = __shfl(e, sl0); int s0 = __shfl(s, sl0);
        float e1 = __shfl(e, sl1); int s1 = __shfl(s, sl1);
        if (e0 != 0.f) {  // ghost slots carry exactly 0
            uint2 q0 = feat8q[(size_t)((unsigned)s0 * 16u + (unsigned)l16)];
            ACC8(q0, e0);
        }
        if (e1 != 0.f) {
            uint2 q1 = feat8q[(size_t)((unsigned)s1 * 16u + (unsigned)l16)];
            ACC8(q1, e1);
        }
    }
    // full denominator per head (reduce over the 8 edge-slot lanes)
    ds += __shfl_xor(ds, 8);
    ds += __shfl_xor(ds, 16);
    ds += __shfl_xor(ds, 32);
    float dfull = __shfl(ds, hacc8);
    float invd = dfull > 0.f ? 1.f / dfull : 0.f;
    // merge the 4 subgroups
#pragma unroll
    for (int i = 0; i < 8; ++i) {
        a[i] += __shfl_xor(a[i], 16);
        a[i] += __shfl_xor(a[i], 32);
    }
    if (sub == 0) {
        uint4 w;
        w.x = packbf(a[0] * invd, a[1] * invd);
        w.y = packbf(a[2] * invd, a[3] * invd);
        w.z = packbf(a[4] * invd, a[5] * invd);
        w.w = packbf(a[6] * invd, a[7] * invd);
        ((uint4*)gatb)[(size_t)node * 16 + l16] = w;
    }
}

// ---- BN stats from bf16 input; contiguous 128-row chunks (782 blocks) ---
__global__ __launch_bounds__(256) void bn_stats(const unsigned* __restrict__ xb,
                                                float* __restrict__ sums, int nrows) {
    int cp = threadIdx.x & 63;   // col pair
    int rr = threadIdx.x >> 6;   // 0..3
    int r0 = blockIdx.x * BNS_ROWS;
    int rend = r0 + BNS_ROWS < nrows ? r0 + BNS_ROWS : nrows;
    float s0 = 0.f, q0 = 0.f, s1 = 0.f, q1 = 0.f;
    for (int r = r0 + rr; r < rend; r += 4) {
        unsigned u = xb[(size_t)r * 64 + cp];
        float a = plo(u), b = phi(u);
        s0 += a; q0 += a * a;
        s1 += b; q1 += b * b;
    }
    __shared__ float red[4][256];
    red[0][threadIdx.x] = s0;
    red[1][threadIdx.x] = q0;
    red[2][threadIdx.x] = s1;
    red[3][threadIdx.x] = q1;
    __syncthreads();
    if (rr == 0) {
        int c0 = cp * 2, c1 = c0 + 1;
        float ts0 = red[0][cp] + red[0][cp + 64] + red[0][cp + 128] + red[0][cp + 192];
        float tq0 = red[1][cp] + red[1][cp + 64] + red[1][cp + 128] + red[1][cp + 192];
        float ts1 = red[2][cp] + red[2][cp + 64] + red[2][cp + 128] + red[2][cp + 192];
        float tq1 = red[3][cp] + red[3][cp + 64] + red[3][cp + 128] + red[3][cp + 192];
        atomicAdd(&sums[c0], ts0);
        atomicAdd(&sums[128 + c0], tq0);
        atomicAdd(&sums[c1], ts1);
        atomicAdd(&sums[128 + c1], tq1);
    }
}

// ---- layer-1 epilogue fused: bn1 + relu + recomputed-h1 residual + pool --
__global__ __launch_bounds__(256) void bn_pool(const unsigned* __restrict__ gat1,
                                               const float* __restrict__ sums1,
                                               const float* __restrict__ g1v,
                                               const float* __restrict__ be1v,
                                               const unsigned* __restrict__ gat0,
                                               const float* __restrict__ sums0,
                                               const float* __restrict__ g0v,
                                               const float* __restrict__ be0v,
                                               const int* __restrict__ gid,
                                               float* __restrict__ pooled) {
    int cp = threadIdx.x & 63;
    int rr = threadIdx.x >> 6;
    int c0 = cp * 2, c1 = c0 + 1;
    float invN = 1.0f / (float)N_NODES;
    float mu10 = sums1[c0] * invN, mu11 = sums1[c1] * invN;
    float rs10 = rsqrtf(sums1[128 + c0] * invN - mu10 * mu10 + EPS);
    float rs11 = rsqrtf(sums1[128 + c1] * invN - mu11 * mu11 + EPS);
    float A10 = rs10 * g1v[c0], B10 = be1v[c0] - mu10 * A10;
    float A11 = rs11 * g1v[c1], B11 = be1v[c1] - mu11 * A11;
    float mu00 = sums0[c0] * invN, mu01 = sums0[c1] * invN;
    float rs00 = rsqrtf(sums0[128 + c0] * invN - mu00 * mu00 + EPS);
    float rs01 = rsqrtf(sums0[128 + c1] * invN - mu01 * mu01 + EPS);
    float A00 = rs00 * g0v[c0], B00 = be0v[c0] - mu00 * A00;
    float A01 = rs01 * g0v[c1], B01 = be0v[c1] - mu01 * A01;
    int r0 = blockIdx.x * BNP_ROWS;
    int rend = r0 + BNP_ROWS < N_NODES ? r0 + BNP_ROWS : N_NODES;
    int r = r0 + rr;
    if (r >= rend) return;
    float a0 = 0.f, a1 = 0.f;
    int cur = gid[r];
    for (; r < rend; r += 4) {
        int gg = gid[r];
        if (gg != cur) {
            atomicAdd(&pooled[cur * HD + c0], a0);
            atomicAdd(&pooled[cur * HD + c1], a1);
            a0 = a1 = 0.f;
            cur = gg;
        }
        unsigned u = gat1[(size_t)r * 64 + cp];
        float z0 = plo(u) * A10 + B10;
        float z1 = phi(u) * A11 + B11;
        z0 = z0 > 0.f ? z0 : 0.f;
        z1 = z1 > 0.f ? z1 : 0.f;
        unsigned v = gat0[(size_t)r * 64 + cp];
        float h0 = plo(v) * A00 + B00;
        float h1 = phi(v) * A01 + B01;
        h0 = h0 > 0.f ? h0 : 0.f;
        h1 = h1 > 0.f ? h1 : 0.f;
        a0 += z0 + h0;
        a1 += z1 + h1;
    }
    atomicAdd(&pooled[cur * HD + c0], a0);
    atomicAdd(&pooled[cur * HD + c1], a1);
}

// ---- masked prediction head ---------------------------------------------
__global__ void pred_kernel(const float* __restrict__ pooled, const float* __restrict__ W,
                            const float* __restrict__ b, const float* __restrict__ mask,
                            float* __restrict__ out) {
    int t = blockIdx.x * blockDim.x + threadIdx.x;
    if (t >= G_GRAPHS * OUT_DIM) return;
    int g = t >> 6, o = t & 63;
    float acc = b[o];
#pragma unroll 4
    for (int c = 0; c < HD; ++c) {
        float m = mask[o * HD + c] > 0.5f ? 1.f : 0.f;
        acc += pooled[g * HD + c] * W[o * HD + c] * m;
    }
    out[t] = acc;
}

extern "C" void kernel_launch(void* const* d_in, const int* in_sizes, int n_in,
                              void* d_out, int out_size, void* d_ws, size_t ws_size,
                              hipStream_t stream) {
    const float* h   = (const float*)d_in[0];
    const int*   src = (const int*)d_in[1];
    const int*   dst = (const int*)d_in[2];
    const int*   gid = (const int*)d_in[3];
    const float* W0  = (const float*)d_in[4];
    const float* al0 = (const float*)d_in[5];
    const float* ar0 = (const float*)d_in[6];
    // d_in[7] = b0 — BN shift-invariance: bias cancels exactly
    const float* g0  = (const float*)d_in[8];
    const float* be0 = (const float*)d_in[9];
    const float* W1  = (const float*)d_in[10];
    const float* al1 = (const float*)d_in[11];
    const float* ar1 = (const float*)d_in[12];
    // d_in[13] = b1 — cancels
    const float* g1  = (const float*)d_in[14];
    const float* be1 = (const float*)d_in[15];
    const float* pW  = (const float*)d_in[16];
    const float* pb  = (const float*)d_in[17];
    const float* msk = (const float*)d_in[18];
    float* out = (float*)d_out;

    // workspace layout
    unsigned short* gat0  = (unsigned short*)d_ws;                 // [N,128] bf16 layer-0 gat out
    unsigned short* gat1  = gat0 + (size_t)N_NODES * HD;           // [N,128] bf16 layer-1 gat out
    unsigned char*  feat8 = (unsigned char*)(gat1 + (size_t)N_NODES * HD); // [N,128] fp8
    float* el   = (float*)(feat8 + (size_t)N_NODES * HD);          // [N,8]
    float* er   = el + (size_t)N_NODES * H;                        // [N,8]
    int2*  ninfo = (int2*)(er + (size_t)N_NODES * H);              // [N] (offs,deg)
    int*   csr_src = (int*)(ninfo + N_NODES);                      // [E]
    int*   bucketCnt = csr_src + N_EDGES;                          // [256]
    float* sums0  = (float*)(bucketCnt + 256);                     // [256]
    float* sums1  = sums0 + 256;                                   // [256]
    float* pooled = sums1 + 256;                                   // [128,128]
    unsigned short* wt0 = (unsigned short*)(pooled + G_GRAPHS * HD); // [144,128] bf16
    unsigned short* wt1 = wt0 + WTROWS * HD;                         // [144,128] bf16
    // pairs aliased over gat1 (8.0 MB < 25.6 MB; dead before layer-1 gat_node writes gat1)
    int*   pairs  = (int*)gat1;

    const int TB = 256;
    dim3 blk(TB);
    int bsc_blocks  = (N_EDGES + 4095) / 4096;
    int node_blocks = (N_NODES + 3) / 4;
    int bns_blocks  = (N_NODES + BNS_ROWS - 1) / BNS_ROWS;
    int bnp_blocks  = (N_NODES + BNP_ROWS - 1) / BNP_ROWS;
    int cw_blocks   = (HD * HD + HD * 16 + TB - 1) / TB;

    // ---------------- CSR build + weight convert (init fused) ------------
    convert_wt<<<cw_blocks, blk, 0, stream>>>(W0, W1, al0, ar0, al1, ar1, wt0, wt1,
                                              bucketCnt, pooled, sums0);
    bucket_scatter<<<bsc_blocks, blk, 0, stream>>>((const int4*)src, (const int4*)dst,
                                                   bucketCnt, pairs);
    bucket_finish<<<NBUCK, blk, 0, stream>>>(bucketCnt, pairs, ninfo, csr_src);

    // ---------------- layer 0 (el/er fused into GEMM; feat fp8) ----------
    gemm_mfma<0><<<GEMM_GRID, blk, 0, stream>>>(h, wt0, (uint2*)feat8, el, er, N_NODES,
                                                nullptr, nullptr, nullptr);
    gat_node<<<node_blocks, blk, 0, stream>>>(ninfo, csr_src, el, er,
                                              (const uint2*)feat8, (unsigned*)gat0);
    bn_stats<<<bns_blocks, blk, 0, stream>>>((const unsigned*)gat0, sums0, N_NODES);

    // ---------------- layer 1 (BN0+ReLU fused into GEMM A-staging) --------
    gemm_mfma<1><<<GEMM_GRID, blk, 0, stream>>>(gat0, wt1, (uint2*)feat8, el, er, N_NODES,
                                                sums0, g0, be0);
    gat_node<<<node_blocks, blk, 0, stream>>>(ninfo, csr_src, el, er,
                                              (const uint2*)feat8, (unsigned*)gat1);
    bn_stats<<<bns_blocks, blk, 0, stream>>>((const unsigned*)gat1, sums1, N_NODES);
    // fused: bn1 + relu + residual(recomputed h1 from gat0) + graph sum-pool
    bn_pool<<<bnp_blocks, blk, 0, stream>>>((const unsigned*)gat1, sums1, g1, be1,
                                            (const unsigned*)gat0, sums0, g0, be0,
                                            gid, pooled);

    // ---------------- head ----------------
    pred_kernel<<<(G_GRAPHS * OUT_DIM + TB - 1) / TB, blk, 0, stream>>>(pooled, pW, pb, msk, out);
}

// Round 13
// 420.383 us; speedup vs baseline: 1.1091x; 1.0235x over previous
//
#include <hip/hip_runtime.h>
#include <cstdint>

#define N_NODES 100000
#define N_EDGES 1600000
#define H 8
#define D 16
#define HD 128
#define G_GRAPHS 128
#define OUT_DIM 64
#define EPS 1e-3f
#define NEG 0.2f
#define NBUCK 196        // ceil(100000/512) dst buckets
#define BSHIFT 9         // 512 nodes per bucket
#define BCAP 10240       // per-bucket edge capacity (mean 8192, sigma~90)
#define MT 64            // GEMM rows per tile
#define APAD 136         // LDS A-tile row stride in halfs
#define NTILES 1563      // ceil(100000/64)
#define GEMM_GRID 512    // == 2 blocks/CU capacity
#define BNP_ROWS 64      // bn_pool rows per block
#define BNS_ROWS 128     // bn_stats rows per block (contiguous chunk)
#define WTROWS 144       // Wt rows: 128 W-cols + 8 el + 8 er
#define SRCMASK 0x1FFFF  // 17-bit src field in packed pair

typedef __attribute__((ext_vector_type(8))) short bf16x8;
typedef __attribute__((ext_vector_type(4))) float f32x4;
typedef __attribute__((ext_vector_type(2))) float f32x2;
typedef __attribute__((ext_vector_type(8))) unsigned short u16x8;

__device__ __forceinline__ unsigned short f2bf(float x) {
    unsigned u = __float_as_uint(x);
    unsigned r = (u + 0x7FFFu + ((u >> 16) & 1u)) >> 16;  // RTNE
    return (unsigned short)r;
}
__device__ __forceinline__ float plo(unsigned q) {  // low bf16 of pair
    return __uint_as_float(q << 16);
}
__device__ __forceinline__ float phi(unsigned q) {  // high bf16 of pair
    return __uint_as_float(q & 0xFFFF0000u);
}
__device__ __forceinline__ unsigned packbf(float a, float b) {
    return (unsigned)f2bf(a) | ((unsigned)f2bf(b) << 16);
}

// decode 8 fp8 (uint2) and accumulate weight ee into a2[0..3] (f32x2 each)
// 4 cvt + 4 v_pk_fma_f32 (packed-f32 math) = 8 VALU ops, was 12.
#define ACC8(qq, ee) do { \
    f32x2 ee2_ = {(ee), (ee)}; \
    f32x2 f0_ = __builtin_amdgcn_cvt_pk_f32_fp8((qq).x, false); \
    f32x2 f1_ = __builtin_amdgcn_cvt_pk_f32_fp8((qq).x, true); \
    f32x2 f2_ = __builtin_amdgcn_cvt_pk_f32_fp8((qq).y, false); \
    f32x2 f3_ = __builtin_amdgcn_cvt_pk_f32_fp8((qq).y, true); \
    a2[0] = __builtin_elementwise_fma(ee2_, f0_, a2[0]); \
    a2[1] = __builtin_elementwise_fma(ee2_, f1_, a2[1]); \
    a2[2] = __builtin_elementwise_fma(ee2_, f2_, a2[2]); \
    a2[3] = __builtin_elementwise_fma(ee2_, f3_, a2[3]); \
} while (0)

// ---- init (fused) + W -> bf16 transposed/PERMUTED + appended wl/wr ------
// Wt row n (n<128) holds W column f = 8*(n&15) + (n>>4): the MFMA output
// lane l16 then owns CONTIGUOUS features 8*l16..8*l16+7 across the 8 tiles,
// so the fp8 pack is lane-local. Rows 128..143: el/er fold (natural order).
__global__ void convert_wt(const float* __restrict__ W0, const float* __restrict__ W1,
                           const float* __restrict__ al0, const float* __restrict__ ar0,
                           const float* __restrict__ al1, const float* __restrict__ ar1,
                           unsigned short* __restrict__ Wt0, unsigned short* __restrict__ Wt1,
                           int* __restrict__ bucketCnt, float* __restrict__ pooled,
                           float* __restrict__ sums01) {
    int t = blockIdx.x * blockDim.x + threadIdx.x;
    if (t < NBUCK) bucketCnt[t] = 0;
    if (t < 512) sums01[t] = 0.f;
    for (int i = t; i < G_GRAPHS * HD; i += gridDim.x * blockDim.x) pooled[i] = 0.f;
    if (t < HD * HD) {
        int k = t >> 7, n = t & 127;
        int f = ((n & 15) << 3) | (n >> 4);  // fp8-pack locality permutation
        Wt0[n * HD + k] = f2bf(W0[k * HD + f]);
        Wt1[n * HD + k] = f2bf(W1[k * HD + f]);
        return;
    }
    int u = t - HD * HD;
    if (u < HD * 16) {
        int k = u >> 4, j = u & 15;
        int h = j & 7;
        const float* a0 = (j < 8) ? al0 : ar0;
        const float* a1 = (j < 8) ? al1 : ar1;
        float s0 = 0.f, s1 = 0.f;
#pragma unroll
        for (int d = 0; d < 16; ++d) {
            s0 += W0[k * HD + h * 16 + d] * a0[h * 16 + d];
            s1 += W1[k * HD + h * 16 + d] * a1[h * 16 + d];
        }
        Wt0[(HD + j) * HD + k] = f2bf(s0);
        Wt1[(HD + j) * HD + k] = f2bf(s1);
    }
}

// ---- CSR build, phase A: bin edges into 196 coarse dst-buckets ----------
// Packed pair: (dstLocal:9b << 17) | (src:17b). int4-vectorized edge loads.
__global__ __launch_bounds__(256) void bucket_scatter(const int4* __restrict__ src4,
                                                      const int4* __restrict__ dst4,
                                                      int* __restrict__ bucketCnt,
                                                      int* __restrict__ pairs) {
    __shared__ int hist[NBUCK];
    __shared__ int cur[NBUCK];
    int t = threadIdx.x;
    if (t < NBUCK) hist[t] = 0;
    __syncthreads();
    int base4 = blockIdx.x * 1024;  // 4096 edges = 1024 int4
    const int NE4 = N_EDGES / 4;    // N_EDGES % 4 == 0
    int4 s[4], d[4];
    int valid[4];
#pragma unroll
    for (int k = 0; k < 4; ++k) {
        int i4 = base4 + t + k * 256;
        if (i4 < NE4) {
            s[k] = src4[i4];
            d[k] = dst4[i4];
            valid[k] = 1;
            atomicAdd(&hist[d[k].x >> BSHIFT], 1);
            atomicAdd(&hist[d[k].y >> BSHIFT], 1);
            atomicAdd(&hist[d[k].z >> BSHIFT], 1);
            atomicAdd(&hist[d[k].w >> BSHIFT], 1);
        } else {
            valid[k] = 0;
        }
    }
    __syncthreads();
    if (t < NBUCK) {
        int c = hist[t];
        cur[t] = (c > 0) ? atomicAdd(&bucketCnt[t], c) : 0;
    }
    __syncthreads();
#pragma unroll
    for (int k = 0; k < 4; ++k) {
        if (valid[k]) {
            int ss[4] = {s[k].x, s[k].y, s[k].z, s[k].w};
            int dd[4] = {d[k].x, d[k].y, d[k].z, d[k].w};
#pragma unroll
            for (int j = 0; j < 4; ++j) {
                int b = dd[j] >> BSHIFT;
                int slot = atomicAdd(&cur[b], 1);
                pairs[(size_t)b * BCAP + slot] = ((dd[j] & 511) << 17) | ss[j];
            }
        }
    }
}

// ---- CSR build, phase B (fused): hist + local scan + global base +
//      ninfo write + placement, per-bucket in one kernel ------------------
__global__ __launch_bounds__(256) void bucket_finish(const int* __restrict__ bucketCnt,
                                                     const int* __restrict__ pairs,
                                                     int2* __restrict__ ninfo,
                                                     int* __restrict__ csr_src) {
    __shared__ int hist[512];
    __shared__ int loc[512];
    __shared__ int bufA[256], bufB[256];
    __shared__ int bbase_sh;
    int b = blockIdx.x, t = threadIdx.x;
    int mycnt = bucketCnt[b];
    int base0 = b << BSHIFT;

    // ---- global bucket base: scan 196 bucket counts (redundant per block)
    bufA[t] = (t < NBUCK) ? bucketCnt[t] : 0;
    __syncthreads();
    {
        int* a = bufA; int* bb = bufB;
        for (int off = 1; off < 256; off <<= 1) {
            int val = a[t];
            if (t >= off) val += a[t - off];
            bb[t] = val;
            __syncthreads();
            int* c = a; a = bb; bb = c;
        }
        if (t == 0) bbase_sh = a[b] - mycnt;  // exclusive base of bucket b
    }
    // ---- per-node hist within bucket (int4-vectorized pairs reads)
    hist[t] = 0;
    hist[t + 256] = 0;
    __syncthreads();
    {
        const int4* p4 = (const int4*)&pairs[(size_t)b * BCAP];
        int n4 = mycnt >> 2;
        for (int i = t; i < n4; i += 256) {
            int4 w = p4[i];
            atomicAdd(&hist[(unsigned)w.x >> 17], 1);
            atomicAdd(&hist[(unsigned)w.y >> 17], 1);
            atomicAdd(&hist[(unsigned)w.z >> 17], 1);
            atomicAdd(&hist[(unsigned)w.w >> 17], 1);
        }
        for (int i = (n4 << 2) + t; i < mycnt; i += 256)
            atomicAdd(&hist[(unsigned)pairs[(size_t)b * BCAP + i] >> 17], 1);
    }
    __syncthreads();
    // ---- 512-entry local exclusive scan (2 elems/thread)
    int s0 = hist[2 * t], s1 = hist[2 * t + 1];
    int ps = s0 + s1;
    bufA[t] = ps;
    __syncthreads();
    int total_excl;
    {
        int* a = bufA; int* bb = bufB;
        for (int off = 1; off < 256; off <<= 1) {
            int val = a[t];
            if (t >= off) val += a[t - off];
            bb[t] = val;
            __syncthreads();
            int* c = a; a = bb; bb = c;
        }
        total_excl = a[t] - ps;  // exclusive pair offset
    }
    int bbase = bbase_sh;
    loc[2 * t] = total_excl;
    loc[2 * t + 1] = total_excl + s0;
    int n0 = base0 + 2 * t, n1 = base0 + 2 * t + 1;
    if (n0 < N_NODES) ninfo[n0] = make_int2(bbase + total_excl, s0);
    if (n1 < N_NODES) ninfo[n1] = make_int2(bbase + total_excl + s0, s1);
    __syncthreads();
    // ---- placement using LDS cursors (loc doubles as cur)
    {
        const int4* p4 = (const int4*)&pairs[(size_t)b * BCAP];
        int n4 = mycnt >> 2;
        for (int i = t; i < n4; i += 256) {
            int4 w = p4[i];
            int ws[4] = {w.x, w.y, w.z, w.w};
#pragma unroll
            for (int j = 0; j < 4; ++j) {
                int dl = (unsigned)ws[j] >> 17;
                int r = atomicAdd(&loc[dl], 1);
                csr_src[bbase + r] = ws[j] & SRCMASK;
            }
        }
        for (int i = (n4 << 2) + t; i < mycnt; i += 256) {
            int w = pairs[(size_t)b * BCAP + i];
            int dl = (unsigned)w >> 17;
            int r = atomicAdd(&loc[dl], 1);
            csr_src[bbase + r] = w & SRCMASK;
        }
    }
}

// ---- GEMM staging: load + convert one tile-row-slice into registers ----
template <int MODE>
__device__ __forceinline__ void stage_load(const void* __restrict__ Xv, int gr, int scol,
                                           int nrows, const float* scs, const float* shs,
                                           u16x8 o[4]) {
    if (gr < nrows) {
        if (MODE == 0) {
            const float* X = (const float*)Xv;
#pragma unroll
            for (int i = 0; i < 4; ++i) {
                float4 va = *(const float4*)&X[(size_t)gr * HD + scol + i * 8];
                float4 vb = *(const float4*)&X[(size_t)gr * HD + scol + i * 8 + 4];
                o[i][0] = f2bf(va.x); o[i][1] = f2bf(va.y);
                o[i][2] = f2bf(va.z); o[i][3] = f2bf(va.w);
                o[i][4] = f2bf(vb.x); o[i][5] = f2bf(vb.y);
                o[i][6] = f2bf(vb.z); o[i][7] = f2bf(vb.w);
            }
        } else {
            const unsigned* X32 = (const unsigned*)Xv;  // bf16 pairs
#pragma unroll
            for (int i = 0; i < 4; ++i) {
                uint4 u = *(const uint4*)&X32[(size_t)gr * 64 + (scol >> 1) + i * 4];
                f32x4 sa = *(const f32x4*)&scs[scol + i * 8];
                f32x4 sb = *(const f32x4*)&scs[scol + i * 8 + 4];
                f32x4 ha = *(const f32x4*)&shs[scol + i * 8];
                f32x4 hb = *(const f32x4*)&shs[scol + i * 8 + 4];
                float z0 = fmaxf(plo(u.x) * sa.x + ha.x, 0.f);
                float z1 = fmaxf(phi(u.x) * sa.y + ha.y, 0.f);
                float z2 = fmaxf(plo(u.y) * sa.z + ha.z, 0.f);
                float z3 = fmaxf(phi(u.y) * sa.w + ha.w, 0.f);
                float z4 = fmaxf(plo(u.z) * sb.x + hb.x, 0.f);
                float z5 = fmaxf(phi(u.z) * sb.y + hb.y, 0.f);
                float z6 = fmaxf(plo(u.w) * sb.z + hb.z, 0.f);
                float z7 = fmaxf(phi(u.w) * sb.w + hb.w, 0.f);
                o[i][0] = f2bf(z0); o[i][1] = f2bf(z1);
                o[i][2] = f2bf(z2); o[i][3] = f2bf(z3);
                o[i][4] = f2bf(z4); o[i][5] = f2bf(z5);
                o[i][6] = f2bf(z6); o[i][7] = f2bf(z7);
            }
        }
    } else {
#pragma unroll
        for (int i = 0; i < 4; ++i) o[i] = (u16x8)0;
    }
}

// ---- MFMA GEMM, 2-deep tile pipeline; feat output packed fp8 e4m3.
// With the Wt permutation, lane l16 holds features 8*l16..8*l16+7 across
// the 8 tiles -> lane-local uint2 pack via v_cvt_pk_fp8_f32.
// el/er fused as 9th output tile (fp32 from accumulators, unchanged).
template <int MODE>
__global__ __launch_bounds__(256, 2) void gemm_mfma(const void* __restrict__ Xv,
                                                    const unsigned short* __restrict__ Wt,
                                                    uint2* __restrict__ Y8,
                                                    float* __restrict__ el,
                                                    float* __restrict__ er,
                                                    int nrows,
                                                    const float* __restrict__ sums,
                                                    const float* __restrict__ gam,
                                                    const float* __restrict__ bet) {
    __shared__ unsigned short As[2][MT * APAD];
    __shared__ __align__(16) float scs[HD];
    __shared__ __align__(16) float shs[HD];
    int tid = threadIdx.x;
    int wave = tid >> 6, lane = tid & 63;
    int qd = lane >> 4, l16 = lane & 15;

    if (MODE == 1) {
        if (tid < HD) {
            float invN = 1.0f / (float)N_NODES;
            float mu = sums[tid] * invN;
            float rs = rsqrtf(sums[HD + tid] * invN - mu * mu + EPS);
            float sc = rs * gam[tid];
            scs[tid] = sc;
            shs[tid] = bet[tid] - mu * sc;
        }
        __syncthreads();
    }

    bf16x8 bfr[9][4];
#pragma unroll
    for (int nt = 0; nt < 9; ++nt)
#pragma unroll
        for (int kb = 0; kb < 4; ++kb)
            bfr[nt][kb] = *(const bf16x8*)&Wt[(nt * 16 + l16) * HD + kb * 32 + qd * 8];

    int srow = tid >> 2, scol = (tid & 3) * 32;  // 4 threads/row, 32 halfs each

    u16x8 o[4];
    int t = blockIdx.x;
    // prologue: stage tile t into buffer 0
    stage_load<MODE>(Xv, t * MT + srow, scol, nrows, scs, shs, o);
#pragma unroll
    for (int i = 0; i < 4; ++i)
        *(u16x8*)&As[0][srow * APAD + scol + i * 8] = o[i];
    __syncthreads();
    int cur = 0;

    for (; t < NTILES; t += gridDim.x) {
        int tn = t + (int)gridDim.x;
        bool more = tn < NTILES;
        // issue next tile's loads (+convert) BEFORE the MFMA burst
        if (more)
            stage_load<MODE>(Xv, tn * MT + srow, scol, nrows, scs, shs, o);
        // compute current tile from As[cur]
        f32x4 acc[9];
#pragma unroll
        for (int nt = 0; nt < 9; ++nt) acc[nt] = (f32x4){0.f, 0.f, 0.f, 0.f};
        bf16x8 afr[4];
#pragma unroll
        for (int kb = 0; kb < 4; ++kb)
            afr[kb] = *(const bf16x8*)&As[cur][(wave * 16 + l16) * APAD + kb * 32 + qd * 8];
#pragma unroll
        for (int nt = 0; nt < 9; ++nt)
#pragma unroll
            for (int kb = 0; kb < 4; ++kb)
                acc[nt] = __builtin_amdgcn_mfma_f32_16x16x32_bf16(afr[kb], bfr[nt][kb], acc[nt], 0, 0, 0);
        int orow = t * MT + wave * 16 + qd * 4;
        if (orow + 3 < nrows) {
#pragma unroll
            for (int r = 0; r < 4; ++r) {
                unsigned lo = 0, hi = 0;
                lo = __builtin_amdgcn_cvt_pk_fp8_f32(acc[0][r], acc[1][r], lo, false);
                lo = __builtin_amdgcn_cvt_pk_fp8_f32(acc[2][r], acc[3][r], lo, true);
                hi = __builtin_amdgcn_cvt_pk_fp8_f32(acc[4][r], acc[5][r], hi, false);
                hi = __builtin_amdgcn_cvt_pk_fp8_f32(acc[6][r], acc[7][r], hi, true);
                Y8[(size_t)(orow + r) * 16 + l16] = make_uint2(lo, hi);
            }
#pragma unroll
            for (int r = 0; r < 4; ++r) {
                float v = acc[8][r];
                if (l16 < 8) el[(orow + r) * 8 + l16] = v;
                else er[(orow + r) * 8 + (l16 - 8)] = v;
            }
        } else {
            for (int r = 0; r < 4; ++r) {
                if (orow + r < nrows) {
                    unsigned lo = 0, hi = 0;
                    lo = __builtin_amdgcn_cvt_pk_fp8_f32(acc[0][r], acc[1][r], lo, false);
                    lo = __builtin_amdgcn_cvt_pk_fp8_f32(acc[2][r], acc[3][r], lo, true);
                    hi = __builtin_amdgcn_cvt_pk_fp8_f32(acc[4][r], acc[5][r], hi, false);
                    hi = __builtin_amdgcn_cvt_pk_fp8_f32(acc[6][r], acc[7][r], hi, true);
                    Y8[(size_t)(orow + r) * 16 + l16] = make_uint2(lo, hi);
                    float v = acc[8][r];
                    if (l16 < 8) el[(orow + r) * 8 + l16] = v;
                    else er[(orow + r) * 8 + (l16 - 8)] = v;
                }
            }
        }
        // write staged tile into the other buffer
        if (more) {
#pragma unroll
            for (int i = 0; i < 4; ++i)
                *(u16x8*)&As[cur ^ 1][srow * APAD + scol + i * 8] = o[i];
        }
        __syncthreads();
        cur ^= 1;
    }
}

// ---- per-dst-node GAT, fp8 feat rows (128 B): 16 lanes/row, one VMEM
// instruction serves 4 edges. Accumulation in packed f32x2 (v_pk_fma_f32).
__global__ __launch_bounds__(256) void gat_node(const int2* __restrict__ ninfo,
                                                const int* __restrict__ csr_src,
                                                const float* __restrict__ el,
                                                const float* __restrict__ er,
                                                const uint2* __restrict__ feat8q,
                                                unsigned* __restrict__ gatb) {
    int node = blockIdx.x * 4 + (threadIdx.x >> 6);
    if (node >= N_NODES) return;
    int lane = threadIdx.x & 63;
    int h7 = lane & 7;        // phase-1 head
    int eidx = lane >> 3;     // phase-1 edge slot (0..7)
    int l16 = lane & 15;      // phase-2 row-lane
    int sub = lane >> 4;      // phase-2 subgroup (slots sub, sub+4)
    int hacc8 = l16 >> 1;     // head of owned features
    int sl0 = sub * 8 + hacc8;    // shfl src for slot sub
    int sl1 = sl0 + 32;           // shfl src for slot sub+4

    int2 pd = ninfo[node];
    int p = pd.x;
    int cnt = pd.y;
    float ern = er[node * 8 + h7];
    float ds = 0.f;
    f32x2 a2[4];
#pragma unroll
    for (int i = 0; i < 4; ++i) a2[i] = (f32x2){0.f, 0.f};

    int nfull = cnt & ~7;
    if (nfull) {
        int s = csr_src[p + eidx];
        float x = el[(unsigned)s * 8u + h7];
        int c = 0;
        for (;;) {
            float v = x + ern;
            v = fmaxf(v, NEG * v);
            float e = __expf(v);
            ds += e;
            int cn = c + 8;
            int snext = 0; float xnext = 0.f;
            if (cn < nfull) {
                snext = csr_src[p + cn + eidx];
                xnext = el[(unsigned)snext * 8u + h7];
            }
            float e0 = __shfl(e, sl0); int s0 = __shfl(s, sl0);
            float e1 = __shfl(e, sl1); int s1 = __shfl(s, sl1);
            uint2 q0 = feat8q[(size_t)((unsigned)s0 * 16u + (unsigned)l16)];
            uint2 q1 = feat8q[(size_t)((unsigned)s1 * 16u + (unsigned)l16)];
            ACC8(q0, e0);
            ACC8(q1, e1);
            if (cn >= nfull) break;
            c = cn; s = snext; x = xnext;
        }
    }
    int rem = cnt & 7;
    if (rem) {
        int s = 0; float e = 0.f;
        if (eidx < rem) {
            s = csr_src[p + nfull + eidx];
            float v = el[(unsigned)s * 8u + h7] + ern;
            v = fmaxf(v, NEG * v);
            e = __expf(v);
        }
        ds += e;
        float e0 = __shfl(e, sl0); int s0 = __shfl(s, sl0);
        float e1 = __shfl(e, sl1); int s1 = __shfl(s, sl1);
        if (e0 != 0.f) {  // ghost slots carry exactly 0
            uint2 q0 = feat8q[(size_t)((unsigned)s0 * 16u + (unsigned)l16)];
            ACC8(q0, e0);
        }
        if (e1 != 0.f) {
            uint2 q1 = feat8q[(size_t)((unsigned)s1 * 16u + (unsigned)l16)];
            ACC8(q1, e1);
        }
    }
    // full denominator per head (reduce over the 8 edge-slot lanes)
    ds += __shfl_xor(ds, 8);
    ds += __shfl_xor(ds, 16);
    ds += __shfl_xor(ds, 32);
    float dfull = __shfl(ds, hacc8);
    float invd = dfull > 0.f ? 1.f / dfull : 0.f;
    // merge the 4 subgroups (elementwise shfl on packed accumulators)
#pragma unroll
    for (int i = 0; i < 4; ++i) {
        a2[i].x += __shfl_xor(a2[i].x, 16);
        a2[i].y += __shfl_xor(a2[i].y, 16);
        a2[i].x += __shfl_xor(a2[i].x, 32);
        a2[i].y += __shfl_xor(a2[i].y, 32);
    }
    if (sub == 0) {
        uint4 w;
        w.x = packbf(a2[0].x * invd, a2[0].y * invd);
        w.y = packbf(a2[1].x * invd, a2[1].y * invd);
        w.z = packbf(a2[2].x * invd, a2[2].y * invd);
        w.w = packbf(a2[3].x * invd, a2[3].y * invd);
        ((uint4*)gatb)[(size_t)node * 16 + l16] = w;
    }
}

// ---- BN stats from bf16 input; contiguous 128-row chunks (782 blocks) ---
__global__ __launch_bounds__(256) void bn_stats(const unsigned* __restrict__ xb,
                                                float* __restrict__ sums, int nrows) {
    int cp = threadIdx.x & 63;   // col pair
    int rr = threadIdx.x >> 6;   // 0..3
    int r0 = blockIdx.x * BNS_ROWS;
    int rend = r0 + BNS_ROWS < nrows ? r0 + BNS_ROWS : nrows;
    float s0 = 0.f, q0 = 0.f, s1 = 0.f, q1 = 0.f;
    for (int r = r0 + rr; r < rend; r += 4) {
        unsigned u = xb[(size_t)r * 64 + cp];
        float a = plo(u), b = phi(u);
        s0 += a; q0 += a * a;
        s1 += b; q1 += b * b;
    }
    __shared__ float red[4][256];
    red[0][threadIdx.x] = s0;
    red[1][threadIdx.x] = q0;
    red[2][threadIdx.x] = s1;
    red[3][threadIdx.x] = q1;
    __syncthreads();
    if (rr == 0) {
        int c0 = cp * 2, c1 = c0 + 1;
        float ts0 = red[0][cp] + red[0][cp + 64] + red[0][cp + 128] + red[0][cp + 192];
        float tq0 = red[1][cp] + red[1][cp + 64] + red[1][cp + 128] + red[1][cp + 192];
        float ts1 = red[2][cp] + red[2][cp + 64] + red[2][cp + 128] + red[2][cp + 192];
        float tq1 = red[3][cp] + red[3][cp + 64] + red[3][cp + 128] + red[3][cp + 192];
        atomicAdd(&sums[c0], ts0);
        atomicAdd(&sums[128 + c0], tq0);
        atomicAdd(&sums[c1], ts1);
        atomicAdd(&sums[128 + c1], tq1);
    }
}

// ---- layer-1 epilogue fused: bn1 + relu + recomputed-h1 residual + pool --
__global__ __launch_bounds__(256) void bn_pool(const unsigned* __restrict__ gat1,
                                               const float* __restrict__ sums1,
                                               const float* __restrict__ g1v,
                                               const float* __restrict__ be1v,
                                               const unsigned* __restrict__ gat0,
                                               const float* __restrict__ sums0,
                                               const float* __restrict__ g0v,
                                               const float* __restrict__ be0v,
                                               const int* __restrict__ gid,
                                               float* __restrict__ pooled) {
    int cp = threadIdx.x & 63;
    int rr = threadIdx.x >> 6;
    int c0 = cp * 2, c1 = c0 + 1;
    float invN = 1.0f / (float)N_NODES;
    float mu10 = sums1[c0] * invN, mu11 = sums1[c1] * invN;
    float rs10 = rsqrtf(sums1[128 + c0] * invN - mu10 * mu10 + EPS);
    float rs11 = rsqrtf(sums1[128 + c1] * invN - mu11 * mu11 + EPS);
    float A10 = rs10 * g1v[c0], B10 = be1v[c0] - mu10 * A10;
    float A11 = rs11 * g1v[c1], B11 = be1v[c1] - mu11 * A11;
    float mu00 = sums0[c0] * invN, mu01 = sums0[c1] * invN;
    float rs00 = rsqrtf(sums0[128 + c0] * invN - mu00 * mu00 + EPS);
    float rs01 = rsqrtf(sums0[128 + c1] * invN - mu01 * mu01 + EPS);
    float A00 = rs00 * g0v[c0], B00 = be0v[c0] - mu00 * A00;
    float A01 = rs01 * g0v[c1], B01 = be0v[c1] - mu01 * A01;
    int r0 = blockIdx.x * BNP_ROWS;
    int rend = r0 + BNP_ROWS < N_NODES ? r0 + BNP_ROWS : N_NODES;
    int r = r0 + rr;
    if (r >= rend) return;
    float a0 = 0.f, a1 = 0.f;
    int cur = gid[r];
    for (; r < rend; r += 4) {
        int gg = gid[r];
        if (gg != cur) {
            atomicAdd(&pooled[cur * HD + c0], a0);
            atomicAdd(&pooled[cur * HD + c1], a1);
            a0 = a1 = 0.f;
            cur = gg;
        }
        unsigned u = gat1[(size_t)r * 64 + cp];
        float z0 = plo(u) * A10 + B10;
        float z1 = phi(u) * A11 + B11;
        z0 = z0 > 0.f ? z0 : 0.f;
        z1 = z1 > 0.f ? z1 : 0.f;
        unsigned v = gat0[(size_t)r * 64 + cp];
        float h0 = plo(v) * A00 + B00;
        float h1 = phi(v) * A01 + B01;
        h0 = h0 > 0.f ? h0 : 0.f;
        h1 = h1 > 0.f ? h1 : 0.f;
        a0 += z0 + h0;
        a1 += z1 + h1;
    }
    atomicAdd(&pooled[cur * HD + c0], a0);
    atomicAdd(&pooled[cur * HD + c1], a1);
}

// ---- masked prediction head ---------------------------------------------
__global__ void pred_kernel(const float* __restrict__ pooled, const float* __restrict__ W,
                            const float* __restrict__ b, const float* __restrict__ mask,
                            float* __restrict__ out) {
    int t = blockIdx.x * blockDim.x + threadIdx.x;
    if (t >= G_GRAPHS * OUT_DIM) return;
    int g = t >> 6, o = t & 63;
    float acc = b[o];
#pragma unroll 4
    for (int c = 0; c < HD; ++c) {
        float m = mask[o * HD + c] > 0.5f ? 1.f : 0.f;
        acc += pooled[g * HD + c] * W[o * HD + c] * m;
    }
    out[t] = acc;
}

extern "C" void kernel_launch(void* const* d_in, const int* in_sizes, int n_in,
                              void* d_out, int out_size, void* d_ws, size_t ws_size,
                              hipStream_t stream) {
    const float* h   = (const float*)d_in[0];
    const int*   src = (const int*)d_in[1];
    const int*   dst = (const int*)d_in[2];
    const int*   gid = (const int*)d_in[3];
    const float* W0  = (const float*)d_in[4];
    const float* al0 = (const float*)d_in[5];
    const float* ar0 = (const float*)d_in[6];
    // d_in[7] = b0 — BN shift-invariance: bias cancels exactly
    const float* g0  = (const float*)d_in[8];
    const float* be0 = (const float*)d_in[9];
    const float* W1  = (const float*)d_in[10];
    const float* al1 = (const float*)d_in[11];
    const float* ar1 = (const float*)d_in[12];
    // d_in[13] = b1 — cancels
    const float* g1  = (const float*)d_in[14];
    const float* be1 = (const float*)d_in[15];
    const float* pW  = (const float*)d_in[16];
    const float* pb  = (const float*)d_in[17];
    const float* msk = (const float*)d_in[18];
    float* out = (float*)d_out;

    // workspace layout
    unsigned short* gat0  = (unsigned short*)d_ws;                 // [N,128] bf16 layer-0 gat out
    unsigned short* gat1  = gat0 + (size_t)N_NODES * HD;           // [N,128] bf16 layer-1 gat out
    unsigned char*  feat8 = (unsigned char*)(gat1 + (size_t)N_NODES * HD); // [N,128] fp8
    float* el   = (float*)(feat8 + (size_t)N_NODES * HD);          // [N,8]
    float* er   = el + (size_t)N_NODES * H;                        // [N,8]
    int2*  ninfo = (int2*)(er + (size_t)N_NODES * H);              // [N] (offs,deg)
    int*   csr_src = (int*)(ninfo + N_NODES);                      // [E]
    int*   bucketCnt = csr_src + N_EDGES;                          // [256]
    float* sums0  = (float*)(bucketCnt + 256);                     // [256]
    float* sums1  = sums0 + 256;                                   // [256]
    float* pooled = sums1 + 256;                                   // [128,128]
    unsigned short* wt0 = (unsigned short*)(pooled + G_GRAPHS * HD); // [144,128] bf16
    unsigned short* wt1 = wt0 + WTROWS * HD;                         // [144,128] bf16
    // pairs aliased over gat1 (8.0 MB < 25.6 MB; dead before layer-1 gat_node writes gat1)
    int*   pairs  = (int*)gat1;

    const int TB = 256;
    dim3 blk(TB);
    int bsc_blocks  = (N_EDGES + 4095) / 4096;
    int node_blocks = (N_NODES + 3) / 4;
    int bns_blocks  = (N_NODES + BNS_ROWS - 1) / BNS_ROWS;
    int bnp_blocks  = (N_NODES + BNP_ROWS - 1) / BNP_ROWS;
    int cw_blocks   = (HD * HD + HD * 16 + TB - 1) / TB;

    // ---------------- CSR build + weight convert (init fused) ------------
    convert_wt<<<cw_blocks, blk, 0, stream>>>(W0, W1, al0, ar0, al1, ar1, wt0, wt1,
                                              bucketCnt, pooled, sums0);
    bucket_scatter<<<bsc_blocks, blk, 0, stream>>>((const int4*)src, (const int4*)dst,
                                                   bucketCnt, pairs);
    bucket_finish<<<NBUCK, blk, 0, stream>>>(bucketCnt, pairs, ninfo, csr_src);

    // ---------------- layer 0 (el/er fused into GEMM; feat fp8) ----------
    gemm_mfma<0><<<GEMM_GRID, blk, 0, stream>>>(h, wt0, (uint2*)feat8, el, er, N_NODES,
                                                nullptr, nullptr, nullptr);
    gat_node<<<node_blocks, blk, 0, stream>>>(ninfo, csr_src, el, er,
                                              (const uint2*)feat8, (unsigned*)gat0);
    bn_stats<<<bns_blocks, blk, 0, stream>>>((const unsigned*)gat0, sums0, N_NODES);

    // ---------------- layer 1 (BN0+ReLU fused into GEMM A-staging) --------
    gemm_mfma<1><<<GEMM_GRID, blk, 0, stream>>>(gat0, wt1, (uint2*)feat8, el, er, N_NODES,
                                                sums0, g0, be0);
    gat_node<<<node_blocks, blk, 0, stream>>>(ninfo, csr_src, el, er,
                                              (const uint2*)feat8, (unsigned*)gat1);
    bn_stats<<<bns_blocks, blk, 0, stream>>>((const unsigned*)gat1, sums1, N_NODES);
    // fused: bn1 + relu + residual(recomputed h1 from gat0) + graph sum-pool
    bn_pool<<<bnp_blocks, blk, 0, stream>>>((const unsigned*)gat1, sums1, g1, be1,
                                            (const unsigned*)gat0, sums0, g0, be0,
                                            gid, pooled);

    // ---------------- head ----------------
    pred_kernel<<<(G_GRAPHS * OUT_DIM + TB - 1) / TB, blk, 0, stream>>>(pooled, pW, pb, msk, out);
}